// Round 2
// baseline (837.389 us; speedup 1.0000x reference)
//
#include <hip/hip_runtime.h>
#include <stdint.h>

#define NI_SMOOTH 0.1f
#define NI_ROUGH  0.05f
#define BETA      0.5f

#define NPASS 9
#define TOUT  2048
#define WBUF  (TOUT + 40)   // 18-halo each side + slack for unconditional +2 reads
#define NTHR  256

// ---- Threefry-2x32 (20 rounds), bit-exact vs JAX's threefry2x32 primitive ----
__host__ __device__ __forceinline__ uint32_t tf_rotl(uint32_t x, int d) {
  return (x << d) | (x >> (32 - d));
}

__host__ __device__ __forceinline__ void threefry2x32(uint32_t k0, uint32_t k1,
                                                      uint32_t x0, uint32_t x1,
                                                      uint32_t* o0, uint32_t* o1) {
  uint32_t ks2 = k0 ^ k1 ^ 0x1BD11BDAu;
  x0 += k0; x1 += k1;
#define TF_R(r) { x0 += x1; x1 = tf_rotl(x1, (r)); x1 ^= x0; }
  TF_R(13) TF_R(15) TF_R(26) TF_R(6)
  x0 += k1;  x1 += ks2 + 1u;
  TF_R(17) TF_R(29) TF_R(16) TF_R(24)
  x0 += ks2; x1 += k0 + 2u;
  TF_R(13) TF_R(15) TF_R(26) TF_R(6)
  x0 += k0;  x1 += k1 + 3u;
  TF_R(17) TF_R(29) TF_R(16) TF_R(24)
  x0 += k1;  x1 += ks2 + 4u;
  TF_R(13) TF_R(15) TF_R(26) TF_R(6)
  x0 += ks2; x1 += k0 + 5u;
#undef TF_R
  *o0 = x0; *o1 = x1;
}

// partitionable random_bits: bits[i] = o0 ^ o1 of threefry(key, (0, i)).
// bernoulli(0.5): uniform < 0.5  <=>  MSB(bits) == 0  -> mask True ("rough").
__device__ __forceinline__ bool tf_rough(uint32_t k0, uint32_t k1, uint32_t c) {
  uint32_t o0, o1;
  threefry2x32(k0, k1, 0u, c, &o0, &o1);
  return ((o0 ^ o1) >> 31) == 0u;
}

__device__ __forceinline__ float upd(float m2, float m1, float c, float p1, float p2,
                                     float yv, bool rough) {
  float stencil = m2 - 4.0f * m1 + 6.0f * c - 4.0f * p1 + p2;
  float term = (1.0f - BETA) * stencil + BETA * (c - yv);
  return rough ? (c + NI_ROUGH * term) : (c - NI_SMOOTH * term);
}

struct Keys { uint32_t k[2 * NPASS]; };

__global__ __launch_bounds__(NTHR) void rs_fused(const float* __restrict__ y,
                                                 float* __restrict__ dst,
                                                 Keys keys, int n) {
  __shared__ float ybuf[WBUF];
  __shared__ float bufA[WBUF];
  __shared__ float bufB[WBUF];

  const int S = blockIdx.x * TOUT;
  const int E = min(S + TOUT, n);
  const int base = S - 18;            // local l  <->  global g = base + l
  const int tid = threadIdx.x;
  const int loadW = (E + 18) - base;  // tile + both halos

  // load y tile (+halo) once; it is both the pass-0 input and the per-pass y term
  for (int l = tid; l < loadW; l += NTHR) {
    int g = base + l;
    if (g >= 0 && g < n) {
      float v = y[g];
      ybuf[l] = v;
      bufA[l] = v;
    }
  }
  __syncthreads();

  float* cur = bufA;
  float* nxt = bufB;
  const bool edge = (blockIdx.x == 0) || (blockIdx.x == gridDim.x - 1);

  for (int p = 0; p < NPASS; ++p) {
    const uint32_t k0 = keys.k[2 * p];
    const uint32_t k1 = keys.k[2 * p + 1];
    const int h = 2 * (NPASS - 1 - p);           // shrinking halo
    const int gA = max(S - h, 0);
    const int gB = min(E + h, n);
    const int lA = gA - base;
    const int lB = gB - base;

    if (!edge) {
      // hot path: pure interior, no per-element branches
      for (int l = lA + tid; l < lB; l += NTHR) {
        const uint32_t c = (uint32_t)(base + l - 2);
        nxt[l] = upd(cur[l - 2], cur[l - 1], cur[l], cur[l + 1], cur[l + 2],
                     ybuf[l], tf_rough(k0, k1, c));
      }
    } else {
      for (int l = lA + tid; l < lB; l += NTHR) {
        const int g = base + l;
        float o;
        if (g == 0) {
          o = cur[l];
        } else if (g == 1) {
          float st = -2.0f * cur[l - 1] + 5.0f * cur[l] - 4.0f * cur[l + 1] + cur[l + 2];
          o = cur[l] + NI_SMOOTH * ((1.0f - BETA) * st + BETA * (cur[l] - ybuf[l]));
        } else if (g >= n - 2) {
          o = ybuf[l];
        } else {
          o = upd(cur[l - 2], cur[l - 1], cur[l], cur[l + 1], cur[l + 2],
                  ybuf[l], tf_rough(k0, k1, (uint32_t)(g - 2)));
        }
        nxt[l] = o;
      }
    }
    __syncthreads();
    float* t = cur; cur = nxt; nxt = t;
  }

  // final tile -> dst
  for (int l = 18 + tid; l < 18 + (E - S); l += NTHR) {
    dst[base + l] = cur[l];
  }
}

extern "C" void kernel_launch(void* const* d_in, const int* in_sizes, int n_in,
                              void* d_out, int out_size, void* d_ws, size_t ws_size,
                              hipStream_t stream) {
  const float* y = (const float*)d_in[0];
  float* out = (float*)d_out;
  int n = in_sizes[0];

  Keys keys;
  for (int k = 0; k < NPASS; ++k) {
    // per-pass key: fold_in(key(42), k) = threefry2x32((0,42), (0,k))  [host math]
    threefry2x32(0u, 42u, 0u, (uint32_t)k, &keys.k[2 * k], &keys.k[2 * k + 1]);
  }

  int blocks = (n + TOUT - 1) / TOUT;
  rs_fused<<<blocks, NTHR, 0, stream>>>(y, out, keys, n);
}

// Round 3
// 564.314 us; speedup vs baseline: 1.4839x; 1.4839x over previous
//
#include <hip/hip_runtime.h>
#include <stdint.h>

#define NPASS 9
#define NTHR  256
#define CPT   8                     // elements per thread, in registers
#define WIDTH (NTHR * CPT)          // 2048 elements per block-tile
#define HALO  20                    // garbage margin (needs >= 2*NPASS = 18; 20 keeps float4 alignment)
#define TOUT  (WIDTH - 2 * HALO)    // 2008 valid outputs per block

// ---- Threefry-2x32 (20 rounds), bit-exact vs JAX threefry2x32, constexpr-capable ----
struct TF2 { uint32_t a, b; };

__host__ __device__ constexpr uint32_t rotl32(uint32_t x, int d) {
  return (x << d) | (x >> (32 - d));
}

__host__ __device__ constexpr TF2 threefry2x32_c(uint32_t k0, uint32_t k1,
                                                 uint32_t x0, uint32_t x1) {
  uint32_t ks2 = k0 ^ k1 ^ 0x1BD11BDAu;
  x0 += k0; x1 += k1;
  x0 += x1; x1 = rotl32(x1, 13); x1 ^= x0;
  x0 += x1; x1 = rotl32(x1, 15); x1 ^= x0;
  x0 += x1; x1 = rotl32(x1, 26); x1 ^= x0;
  x0 += x1; x1 = rotl32(x1, 6);  x1 ^= x0;
  x0 += k1; x1 += ks2 + 1u;
  x0 += x1; x1 = rotl32(x1, 17); x1 ^= x0;
  x0 += x1; x1 = rotl32(x1, 29); x1 ^= x0;
  x0 += x1; x1 = rotl32(x1, 16); x1 ^= x0;
  x0 += x1; x1 = rotl32(x1, 24); x1 ^= x0;
  x0 += ks2; x1 += k0 + 2u;
  x0 += x1; x1 = rotl32(x1, 13); x1 ^= x0;
  x0 += x1; x1 = rotl32(x1, 15); x1 ^= x0;
  x0 += x1; x1 = rotl32(x1, 26); x1 ^= x0;
  x0 += x1; x1 = rotl32(x1, 6);  x1 ^= x0;
  x0 += k0; x1 += k1 + 3u;
  x0 += x1; x1 = rotl32(x1, 17); x1 ^= x0;
  x0 += x1; x1 = rotl32(x1, 29); x1 ^= x0;
  x0 += x1; x1 = rotl32(x1, 16); x1 ^= x0;
  x0 += x1; x1 = rotl32(x1, 24); x1 ^= x0;
  x0 += k1; x1 += ks2 + 4u;
  x0 += x1; x1 = rotl32(x1, 13); x1 ^= x0;
  x0 += x1; x1 = rotl32(x1, 15); x1 ^= x0;
  x0 += x1; x1 = rotl32(x1, 26); x1 ^= x0;
  x0 += x1; x1 = rotl32(x1, 6);  x1 ^= x0;
  x0 += ks2; x1 += k0 + 5u;
  return TF2{x0, x1};
}

// Per-pass expanded constants: C0 = x0-init, C1 = x1-key, C2..C11 = 5 key injections.
struct PassConsts { uint32_t c[12]; };

__host__ __device__ constexpr PassConsts make_pc(int k) {
  // fold_in(key(42), k) = threefry2x32((0,42), (0,k))
  TF2 kk = threefry2x32_c(0u, 42u, 0u, (uint32_t)k);
  uint32_t k0 = kk.a, k1 = kk.b;
  uint32_t ks2 = k0 ^ k1 ^ 0x1BD11BDAu;
  return PassConsts{{ k0, k1,
                      k1, ks2 + 1u,
                      ks2, k0 + 2u,
                      k0, k1 + 3u,
                      k1, ks2 + 4u,
                      ks2, k0 + 5u }};
}

constexpr PassConsts PC[NPASS] = {
  make_pc(0), make_pc(1), make_pc(2), make_pc(3), make_pc(4),
  make_pc(5), make_pc(6), make_pc(7), make_pc(8)
};

// partitionable random_bits: bits[i] = o0 ^ o1 of threefry(key, (0, i));
// bernoulli(0.5): uniform < 0.5  <=>  MSB == 0  -> "rough". x1 arrives pre-keyed (c + C[1]).
__device__ __forceinline__ bool rough_hash(uint32_t x1, const uint32_t* C) {
  uint32_t x0 = C[0];
#define TF_R(r) { x0 += x1; x1 = (x1 << (r)) | (x1 >> (32 - (r))); x1 ^= x0; }
  TF_R(13) TF_R(15) TF_R(26) TF_R(6)
  x0 += C[2];  x1 += C[3];
  TF_R(17) TF_R(29) TF_R(16) TF_R(24)
  x0 += C[4];  x1 += C[5];
  TF_R(13) TF_R(15) TF_R(26) TF_R(6)
  x0 += C[6];  x1 += C[7];
  TF_R(17) TF_R(29) TF_R(16) TF_R(24)
  x0 += C[8];  x1 += C[9];
  TF_R(13) TF_R(15) TF_R(26) TF_R(6)
  x0 += C[10]; x1 += C[11];
#undef TF_R
  return (int)(x0 ^ x1) >= 0;
}

__device__ __forceinline__ float upd_sel(float m2, float m1, float c, float p1, float p2,
                                         float yv, bool rough) {
  float stencil = m2 - 4.0f * m1 + 6.0f * c - 4.0f * p1 + p2;
  float term = 0.5f * stencil + 0.5f * (c - yv);
  float ni = rough ? 0.05f : -0.1f;   // +NI_ROUGH : -NI_SMOOTH
  return c + ni * term;
}

__global__ __launch_bounds__(NTHR) void rs_fused(const float* __restrict__ y,
                                                 float* __restrict__ dst, int n) {
  __shared__ float sm[3 * WIDTH];     // fast path uses [0, 2*NTHR*5); edge path uses all 3*WIDTH
  const int bid = blockIdx.x, tid = threadIdx.x;
  const int S = bid * TOUT;
  const int E = min(S + TOUT, n);
  if (E <= S) return;

  const bool fast = (bid > 0) && (S - HALO + WIDTH <= n) && (E <= n - 2);

  if (fast) {
    const int gbase = S - HALO + tid * CPT;            // 16B-aligned (S%4==0, HALO%4==0)
    const float4 ylo = *(const float4*)(y + gbase);
    const float4 yhi = *(const float4*)(y + gbase + 4);
    const float y0 = ylo.x, y1 = ylo.y, y2 = ylo.z, y3 = ylo.w;
    const float y4 = yhi.x, y5 = yhi.y, y6 = yhi.z, y7 = yhi.w;
    float v0 = y0, v1 = y1, v2 = y2, v3 = y3, v4 = y4, v5 = y5, v6 = y6, v7 = y7;
    const uint32_t cb = (uint32_t)(gbase - 2);         // mask counter base (g-2)

    // stride-5 LDS slots -> 2-way bank aliasing (free); addresses fixed across passes
    const int wsl = tid * 5;
    const int wl  = (tid == 0 ? 0 : tid - 1) * 5;
    const int wr  = (tid == NTHR - 1 ? NTHR - 1 : tid + 1) * 5;

#pragma unroll 1
    for (int p = 0; p < NPASS; ++p) {
      const uint32_t* C = PC[p].c;
      const uint32_t x1b = cb + C[1];
      float* hb = sm + (p & 1) * (NTHR * 5);           // double-buffered: 1 sync per pass
      hb[wsl + 0] = v0; hb[wsl + 1] = v1; hb[wsl + 2] = v6; hb[wsl + 3] = v7;
      __syncthreads();
      float lh0 = hb[wl + 2], lh1 = hb[wl + 3];
      float rh0 = hb[wr + 0], rh1 = hb[wr + 1];
      if (tid == 0)        { lh0 = v0; lh1 = v1; }     // garbage margin, any finite value
      if (tid == NTHR - 1) { rh0 = v6; rh1 = v7; }

      const float n0 = upd_sel(lh0, lh1, v0, v1, v2, y0, rough_hash(x1b + 0u, C));
      const float n1 = upd_sel(lh1, v0, v1, v2, v3, y1, rough_hash(x1b + 1u, C));
      const float n2 = upd_sel(v0, v1, v2, v3, v4, y2, rough_hash(x1b + 2u, C));
      const float n3 = upd_sel(v1, v2, v3, v4, v5, y3, rough_hash(x1b + 3u, C));
      const float n4 = upd_sel(v2, v3, v4, v5, v6, y4, rough_hash(x1b + 4u, C));
      const float n5 = upd_sel(v3, v4, v5, v6, v7, y5, rough_hash(x1b + 5u, C));
      const float n6 = upd_sel(v4, v5, v6, v7, rh0, y6, rough_hash(x1b + 6u, C));
      const float n7 = upd_sel(v5, v6, v7, rh0, rh1, y7, rough_hash(x1b + 7u, C));
      v0 = n0; v1 = n1; v2 = n2; v3 = n3; v4 = n4; v5 = n5; v6 = n6; v7 = n7;
    }

    const int l0 = tid * CPT;
    if (l0 >= HALO && l0 + CPT <= HALO + TOUT) {
      *(float4*)(dst + gbase)     = make_float4(v0, v1, v2, v3);
      *(float4*)(dst + gbase + 4) = make_float4(v4, v5, v6, v7);
    } else {
      const float vv[CPT] = {v0, v1, v2, v3, v4, v5, v6, v7};
#pragma unroll
      for (int j = 0; j < CPT; ++j) {
        const int l = l0 + j;
        if (l >= HALO && l < HALO + TOUT) dst[gbase + j] = vv[j];
      }
    }
  } else {
    // edge blocks (first/last): LDS-walk path with exact boundary semantics
    float* ybuf = sm;
    float* bufA = sm + WIDTH;
    float* bufB = sm + 2 * WIDTH;
    const int base = S - HALO;
    const int loadW = min(E + HALO, n) - base;
    for (int l = tid; l < loadW; l += NTHR) {
      const int g = base + l;
      if (g >= 0) { const float t = y[g]; ybuf[l] = t; bufA[l] = t; }
    }
    __syncthreads();

    float* cur = bufA;
    float* nxt = bufB;
#pragma unroll 1
    for (int p = 0; p < NPASS; ++p) {
      const uint32_t* C = PC[p].c;
      const int h = 2 * (NPASS - 1 - p);
      const int gA = max(S - h, 0), gB = min(E + h, n);
      const int lA = gA - base, lB = gB - base;
      for (int l = lA + tid; l < lB; l += NTHR) {
        const int g = base + l;
        float o;
        if (g == 0) {
          o = cur[l];
        } else if (g == 1) {
          const float st = -2.0f * cur[l - 1] + 5.0f * cur[l] - 4.0f * cur[l + 1] + cur[l + 2];
          o = cur[l] + 0.1f * (0.5f * st + 0.5f * (cur[l] - ybuf[l]));
        } else if (g >= n - 2) {
          o = ybuf[l];
        } else {
          o = upd_sel(cur[l - 2], cur[l - 1], cur[l], cur[l + 1], cur[l + 2], ybuf[l],
                      rough_hash((uint32_t)(g - 2) + C[1], C));
        }
        nxt[l] = o;
      }
      __syncthreads();
      float* t = cur; cur = nxt; nxt = t;
    }
    for (int l = HALO + tid; l < HALO + (E - S); l += NTHR) dst[base + l] = cur[l];
  }
}

extern "C" void kernel_launch(void* const* d_in, const int* in_sizes, int n_in,
                              void* d_out, int out_size, void* d_ws, size_t ws_size,
                              hipStream_t stream) {
  const float* y = (const float*)d_in[0];
  float* out = (float*)d_out;
  const int n = in_sizes[0];
  const int blocks = (n + TOUT - 1) / TOUT;
  rs_fused<<<blocks, NTHR, 0, stream>>>(y, out, n);
}

// Round 4
// 564.081 us; speedup vs baseline: 1.4845x; 1.0004x over previous
//
#include <hip/hip_runtime.h>
#include <stdint.h>

#define NPASS 9
#define NTHR  256
#define CPT   8                     // elements per thread, in registers
#define WIDTH (NTHR * CPT)          // 2048 elements per block-tile
#define HALO  20                    // garbage margin (needs >= 2*NPASS = 18; 20 keeps float4 alignment)
#define TOUT  (WIDTH - 2 * HALO)    // 2008 valid outputs per block

// ---- Threefry-2x32 (20 rounds), bit-exact vs JAX threefry2x32, constexpr-capable ----
struct TF2 { uint32_t a, b; };

__host__ __device__ constexpr uint32_t rotl32(uint32_t x, int d) {
  return (x << d) | (x >> (32 - d));
}

__host__ __device__ constexpr TF2 threefry2x32_c(uint32_t k0, uint32_t k1,
                                                 uint32_t x0, uint32_t x1) {
  uint32_t ks2 = k0 ^ k1 ^ 0x1BD11BDAu;
  x0 += k0; x1 += k1;
  x0 += x1; x1 = rotl32(x1, 13); x1 ^= x0;
  x0 += x1; x1 = rotl32(x1, 15); x1 ^= x0;
  x0 += x1; x1 = rotl32(x1, 26); x1 ^= x0;
  x0 += x1; x1 = rotl32(x1, 6);  x1 ^= x0;
  x0 += k1; x1 += ks2 + 1u;
  x0 += x1; x1 = rotl32(x1, 17); x1 ^= x0;
  x0 += x1; x1 = rotl32(x1, 29); x1 ^= x0;
  x0 += x1; x1 = rotl32(x1, 16); x1 ^= x0;
  x0 += x1; x1 = rotl32(x1, 24); x1 ^= x0;
  x0 += ks2; x1 += k0 + 2u;
  x0 += x1; x1 = rotl32(x1, 13); x1 ^= x0;
  x0 += x1; x1 = rotl32(x1, 15); x1 ^= x0;
  x0 += x1; x1 = rotl32(x1, 26); x1 ^= x0;
  x0 += x1; x1 = rotl32(x1, 6);  x1 ^= x0;
  x0 += k0; x1 += k1 + 3u;
  x0 += x1; x1 = rotl32(x1, 17); x1 ^= x0;
  x0 += x1; x1 = rotl32(x1, 29); x1 ^= x0;
  x0 += x1; x1 = rotl32(x1, 16); x1 ^= x0;
  x0 += x1; x1 = rotl32(x1, 24); x1 ^= x0;
  x0 += k1; x1 += ks2 + 4u;
  x0 += x1; x1 = rotl32(x1, 13); x1 ^= x0;
  x0 += x1; x1 = rotl32(x1, 15); x1 ^= x0;
  x0 += x1; x1 = rotl32(x1, 26); x1 ^= x0;
  x0 += x1; x1 = rotl32(x1, 6);  x1 ^= x0;
  x0 += ks2; x1 += k0 + 5u;
  return TF2{x0, x1};
}

// Per-pass expanded constants: C0 = x0-init, C1 = x1-key, C2..C11 = 5 key injections.
struct PassConsts { uint32_t c[12]; };

__host__ __device__ constexpr PassConsts make_pc(int k) {
  // fold_in(key(42), k) = threefry2x32((0,42), (0,k))
  TF2 kk = threefry2x32_c(0u, 42u, 0u, (uint32_t)k);
  uint32_t k0 = kk.a, k1 = kk.b;
  uint32_t ks2 = k0 ^ k1 ^ 0x1BD11BDAu;
  return PassConsts{{ k0, k1,
                      k1, ks2 + 1u,
                      ks2, k0 + 2u,
                      k0, k1 + 3u,
                      k1, ks2 + 4u,
                      ks2, k0 + 5u }};
}

constexpr PassConsts PC[NPASS] = {
  make_pc(0), make_pc(1), make_pc(2), make_pc(3), make_pc(4),
  make_pc(5), make_pc(6), make_pc(7), make_pc(8)
};

// single-instruction rotate: v_alignbit_b32 (a:b >> c) with a==b == rotr(x, c),
// so rotl(x, r) == alignbit(x, x, 32-r)
__device__ __forceinline__ uint32_t rotl_a(uint32_t x, int r) {
  return __builtin_amdgcn_alignbit(x, x, 32 - r);
}

// partitionable random_bits: bits[i] = o0 ^ o1 of threefry(key, (0, i));
// bernoulli(0.5): uniform < 0.5  <=>  MSB == 0  -> "rough". x1 arrives pre-keyed (c + C[1]).
__device__ __forceinline__ bool rough_hash(uint32_t x1, const uint32_t* C) {
  uint32_t x0 = C[0];
#define TF_R(r) { x0 += x1; x1 = rotl_a(x1, (r)); x1 ^= x0; }
  TF_R(13) TF_R(15) TF_R(26) TF_R(6)
  x0 += C[2];  x1 += C[3];
  TF_R(17) TF_R(29) TF_R(16) TF_R(24)
  x0 += C[4];  x1 += C[5];
  TF_R(13) TF_R(15) TF_R(26) TF_R(6)
  x0 += C[6];  x1 += C[7];
  TF_R(17) TF_R(29) TF_R(16) TF_R(24)
  x0 += C[8];  x1 += C[9];
  TF_R(13) TF_R(15) TF_R(26) TF_R(6)
  x0 += C[10]; x1 += C[11];
#undef TF_R
  return (int)(x0 ^ x1) >= 0;
}

__device__ __forceinline__ float upd_sel(float m2, float m1, float c, float p1, float p2,
                                         float yv, bool rough) {
  float stencil = m2 - 4.0f * m1 + 6.0f * c - 4.0f * p1 + p2;
  float term = 0.5f * stencil + 0.5f * (c - yv);
  float ni = rough ? 0.05f : -0.1f;   // +NI_ROUGH : -NI_SMOOTH
  return c + ni * term;
}

__global__ __launch_bounds__(NTHR) void rs_fused(const float* __restrict__ y,
                                                 float* __restrict__ dst, int n) {
  __shared__ float sm[3 * WIDTH];     // fast path uses [0, 2*NTHR*5); edge path uses all 3*WIDTH
  const int bid = blockIdx.x, tid = threadIdx.x;
  const int S = bid * TOUT;
  const int E = min(S + TOUT, n);
  if (E <= S) return;

  const bool fast = (bid > 0) && (S - HALO + WIDTH <= n) && (E <= n - 2);

  if (fast) {
    const int gbase = S - HALO + tid * CPT;            // 16B-aligned (S%4==0, HALO%4==0)
    const float4 ylo = *(const float4*)(y + gbase);
    const float4 yhi = *(const float4*)(y + gbase + 4);
    const float y0 = ylo.x, y1 = ylo.y, y2 = ylo.z, y3 = ylo.w;
    const float y4 = yhi.x, y5 = yhi.y, y6 = yhi.z, y7 = yhi.w;
    float v0 = y0, v1 = y1, v2 = y2, v3 = y3, v4 = y4, v5 = y5, v6 = y6, v7 = y7;
    const uint32_t cb = (uint32_t)(gbase - 2);         // mask counter base (g-2)

    // stride-5 LDS slots -> 2-way bank aliasing (free); addresses fixed across passes
    const int wsl = tid * 5;
    const int wl  = (tid == 0 ? 0 : tid - 1) * 5;
    const int wr  = (tid == NTHR - 1 ? NTHR - 1 : tid + 1) * 5;

#pragma unroll 1
    for (int p = 0; p < NPASS; ++p) {
      const uint32_t* C = PC[p].c;
      const uint32_t x1b = cb + C[1];
      float* hb = sm + (p & 1) * (NTHR * 5);           // double-buffered: 1 sync per pass
      hb[wsl + 0] = v0; hb[wsl + 1] = v1; hb[wsl + 2] = v6; hb[wsl + 3] = v7;
      __syncthreads();
      float lh0 = hb[wl + 2], lh1 = hb[wl + 3];
      float rh0 = hb[wr + 0], rh1 = hb[wr + 1];
      if (tid == 0)        { lh0 = v0; lh1 = v1; }     // garbage margin, any finite value
      if (tid == NTHR - 1) { rh0 = v6; rh1 = v7; }

      const float n0 = upd_sel(lh0, lh1, v0, v1, v2, y0, rough_hash(x1b + 0u, C));
      const float n1 = upd_sel(lh1, v0, v1, v2, v3, y1, rough_hash(x1b + 1u, C));
      const float n2 = upd_sel(v0, v1, v2, v3, v4, y2, rough_hash(x1b + 2u, C));
      const float n3 = upd_sel(v1, v2, v3, v4, v5, y3, rough_hash(x1b + 3u, C));
      const float n4 = upd_sel(v2, v3, v4, v5, v6, y4, rough_hash(x1b + 4u, C));
      const float n5 = upd_sel(v3, v4, v5, v6, v7, y5, rough_hash(x1b + 5u, C));
      const float n6 = upd_sel(v4, v5, v6, v7, rh0, y6, rough_hash(x1b + 6u, C));
      const float n7 = upd_sel(v5, v6, v7, rh0, rh1, y7, rough_hash(x1b + 7u, C));
      v0 = n0; v1 = n1; v2 = n2; v3 = n3; v4 = n4; v5 = n5; v6 = n6; v7 = n7;
    }

    const int l0 = tid * CPT;
    if (l0 >= HALO && l0 + CPT <= HALO + TOUT) {
      *(float4*)(dst + gbase)     = make_float4(v0, v1, v2, v3);
      *(float4*)(dst + gbase + 4) = make_float4(v4, v5, v6, v7);
    } else {
      const float vv[CPT] = {v0, v1, v2, v3, v4, v5, v6, v7};
#pragma unroll
      for (int j = 0; j < CPT; ++j) {
        const int l = l0 + j;
        if (l >= HALO && l < HALO + TOUT) dst[gbase + j] = vv[j];
      }
    }
  } else {
    // edge blocks (first/last): LDS-walk path with exact boundary semantics
    float* ybuf = sm;
    float* bufA = sm + WIDTH;
    float* bufB = sm + 2 * WIDTH;
    const int base = S - HALO;
    const int loadW = min(E + HALO, n) - base;
    for (int l = tid; l < loadW; l += NTHR) {
      const int g = base + l;
      if (g >= 0) { const float t = y[g]; ybuf[l] = t; bufA[l] = t; }
    }
    __syncthreads();

    float* cur = bufA;
    float* nxt = bufB;
#pragma unroll 1
    for (int p = 0; p < NPASS; ++p) {
      const uint32_t* C = PC[p].c;
      const int h = 2 * (NPASS - 1 - p);
      const int gA = max(S - h, 0), gB = min(E + h, n);
      const int lA = gA - base, lB = gB - base;
      for (int l = lA + tid; l < lB; l += NTHR) {
        const int g = base + l;
        float o;
        if (g == 0) {
          o = cur[l];
        } else if (g == 1) {
          const float st = -2.0f * cur[l - 1] + 5.0f * cur[l] - 4.0f * cur[l + 1] + cur[l + 2];
          o = cur[l] + 0.1f * (0.5f * st + 0.5f * (cur[l] - ybuf[l]));
        } else if (g >= n - 2) {
          o = ybuf[l];
        } else {
          o = upd_sel(cur[l - 2], cur[l - 1], cur[l], cur[l + 1], cur[l + 2], ybuf[l],
                      rough_hash((uint32_t)(g - 2) + C[1], C));
        }
        nxt[l] = o;
      }
      __syncthreads();
      float* t = cur; cur = nxt; nxt = t;
    }
    for (int l = HALO + tid; l < HALO + (E - S); l += NTHR) dst[base + l] = cur[l];
  }
}

extern "C" void kernel_launch(void* const* d_in, const int* in_sizes, int n_in,
                              void* d_out, int out_size, void* d_ws, size_t ws_size,
                              hipStream_t stream) {
  const float* y = (const float*)d_in[0];
  float* out = (float*)d_out;
  const int n = in_sizes[0];
  const int blocks = (n + TOUT - 1) / TOUT;
  rs_fused<<<blocks, NTHR, 0, stream>>>(y, out, n);
}

// Round 5
// 562.390 us; speedup vs baseline: 1.4890x; 1.0030x over previous
//
#include <hip/hip_runtime.h>
#include <stdint.h>

#define NPASS 9
#define NTHR  256
#define CPT   8                     // elements per thread, in registers
#define WIDTH (NTHR * CPT)          // 2048 elements per block-tile
#define HALO  20                    // garbage margin (needs >= 2*NPASS = 18; 20 keeps float4 alignment)
#define TOUT  (WIDTH - 2 * HALO)    // 2008 valid outputs per block

// ---- Threefry-2x32 (20 rounds), bit-exact vs JAX threefry2x32, constexpr-capable ----
struct TF2 { uint32_t a, b; };

__host__ __device__ constexpr uint32_t rotl32(uint32_t x, int d) {
  return (x << d) | (x >> (32 - d));
}

__host__ __device__ constexpr TF2 threefry2x32_c(uint32_t k0, uint32_t k1,
                                                 uint32_t x0, uint32_t x1) {
  uint32_t ks2 = k0 ^ k1 ^ 0x1BD11BDAu;
  x0 += k0; x1 += k1;
  x0 += x1; x1 = rotl32(x1, 13); x1 ^= x0;
  x0 += x1; x1 = rotl32(x1, 15); x1 ^= x0;
  x0 += x1; x1 = rotl32(x1, 26); x1 ^= x0;
  x0 += x1; x1 = rotl32(x1, 6);  x1 ^= x0;
  x0 += k1; x1 += ks2 + 1u;
  x0 += x1; x1 = rotl32(x1, 17); x1 ^= x0;
  x0 += x1; x1 = rotl32(x1, 29); x1 ^= x0;
  x0 += x1; x1 = rotl32(x1, 16); x1 ^= x0;
  x0 += x1; x1 = rotl32(x1, 24); x1 ^= x0;
  x0 += ks2; x1 += k0 + 2u;
  x0 += x1; x1 = rotl32(x1, 13); x1 ^= x0;
  x0 += x1; x1 = rotl32(x1, 15); x1 ^= x0;
  x0 += x1; x1 = rotl32(x1, 26); x1 ^= x0;
  x0 += x1; x1 = rotl32(x1, 6);  x1 ^= x0;
  x0 += k0; x1 += k1 + 3u;
  x0 += x1; x1 = rotl32(x1, 17); x1 ^= x0;
  x0 += x1; x1 = rotl32(x1, 29); x1 ^= x0;
  x0 += x1; x1 = rotl32(x1, 16); x1 ^= x0;
  x0 += x1; x1 = rotl32(x1, 24); x1 ^= x0;
  x0 += k1; x1 += ks2 + 4u;
  x0 += x1; x1 = rotl32(x1, 13); x1 ^= x0;
  x0 += x1; x1 = rotl32(x1, 15); x1 ^= x0;
  x0 += x1; x1 = rotl32(x1, 26); x1 ^= x0;
  x0 += x1; x1 = rotl32(x1, 6);  x1 ^= x0;
  x0 += ks2; x1 += k0 + 5u;
  return TF2{x0, x1};
}

// Per-pass expanded constants: C0 = x0-init, C1 = x1-key, C2..C11 = 5 key injections.
struct PassConsts { uint32_t c[12]; };

__host__ __device__ constexpr PassConsts make_pc(int k) {
  // fold_in(key(42), k) = threefry2x32((0,42), (0,k))
  TF2 kk = threefry2x32_c(0u, 42u, 0u, (uint32_t)k);
  uint32_t k0 = kk.a, k1 = kk.b;
  uint32_t ks2 = k0 ^ k1 ^ 0x1BD11BDAu;
  return PassConsts{{ k0, k1,
                      k1, ks2 + 1u,
                      ks2, k0 + 2u,
                      k0, k1 + 3u,
                      k1, ks2 + 4u,
                      ks2, k0 + 5u }};
}

constexpr PassConsts PC[NPASS] = {
  make_pc(0), make_pc(1), make_pc(2), make_pc(3), make_pc(4),
  make_pc(5), make_pc(6), make_pc(7), make_pc(8)
};

__device__ __forceinline__ uint32_t rotl_a(uint32_t x, int r) {
  return __builtin_amdgcn_alignbit(x, x, 32 - r);
}

// partitionable random_bits: bits[i] = o0 ^ o1 of threefry(key, (0, i));
// bernoulli(0.5): uniform < 0.5  <=>  MSB == 0  -> "rough". x1 arrives pre-keyed (c + C[1]).
__device__ __forceinline__ bool rough_hash(uint32_t x1, const uint32_t* C) {
  uint32_t x0 = C[0];
#define TF_R(r) { x0 += x1; x1 = rotl_a(x1, (r)); x1 ^= x0; }
  TF_R(13) TF_R(15) TF_R(26) TF_R(6)
  x0 += C[2];  x1 += C[3];
  TF_R(17) TF_R(29) TF_R(16) TF_R(24)
  x0 += C[4];  x1 += C[5];
  TF_R(13) TF_R(15) TF_R(26) TF_R(6)
  x0 += C[6];  x1 += C[7];
  TF_R(17) TF_R(29) TF_R(16) TF_R(24)
  x0 += C[8];  x1 += C[9];
  TF_R(13) TF_R(15) TF_R(26) TF_R(6)
  x0 += C[10]; x1 += C[11];
#undef TF_R
  return (int)(x0 ^ x1) >= 0;
}

// out = c + ni*(0.5*st + 0.5*(c-y)) reassociated to c + (0.5*ni)*(st + (c-y)).
// rough: ni=+0.05 -> k=+0.025 ; smooth: ni=-0.1 -> k=-0.05
__device__ __forceinline__ float upd_sel(float m2, float m1, float c, float p1, float p2,
                                         float yv, bool rough) {
  float st = m2 - 4.0f * m1 + 6.0f * c - 4.0f * p1 + p2;
  float tt = st + (c - yv);
  float k = rough ? 0.025f : -0.05f;
  return c + k * tt;
}

__global__ __launch_bounds__(NTHR, 8) void rs_fused(const float* __restrict__ y,
                                                    float* __restrict__ dst, int n) {
  __shared__ float hb2[2 * NTHR * 5];   // halo-exchange double buffer only (10240 B)
  const int bid = blockIdx.x, tid = threadIdx.x;
  const int S = bid * TOUT;
  const int E = min(S + TOUT, n);
  if (E <= S) return;

  const int gbase = S - HALO + tid * CPT;   // 16B-aligned when in-range
  const bool fast = (bid > 0) && (S - HALO + WIDTH <= n) && (E <= n - 2);

  float y0, y1, y2, y3, y4, y5, y6, y7;
  if (fast) {
    const float4 ylo = *(const float4*)(y + gbase);
    const float4 yhi = *(const float4*)(y + gbase + 4);
    y0 = ylo.x; y1 = ylo.y; y2 = ylo.z; y3 = ylo.w;
    y4 = yhi.x; y5 = yhi.y; y6 = yhi.z; y7 = yhi.w;
  } else {
    // clamped scalar loads; OOB slots hold finite garbage in the margin
    float yy[CPT];
#pragma unroll
    for (int j = 0; j < CPT; ++j) {
      int g = gbase + j;
      g = g < 0 ? 0 : (g > n - 1 ? n - 1 : g);
      yy[j] = y[g];
    }
    y0 = yy[0]; y1 = yy[1]; y2 = yy[2]; y3 = yy[3];
    y4 = yy[4]; y5 = yy[5]; y6 = yy[6]; y7 = yy[7];
  }
  float v0 = y0, v1 = y1, v2 = y2, v3 = y3, v4 = y4, v5 = y5, v6 = y6, v7 = y7;

  const uint32_t cb = (uint32_t)(gbase - 2);     // mask counter base (g-2)

  // stride-5 LDS slots -> 2-way bank aliasing (free); addresses fixed across passes.
  // Clamped wl/wr at block edges read own slot -> finite garbage in the margin.
  const int wsl = tid * 5;
  const int wl  = (tid == 0 ? 0 : tid - 1) * 5;
  const int wr  = (tid == NTHR - 1 ? NTHR - 1 : tid + 1) * 5;

  if (fast) {
#pragma unroll 1
    for (int p = 0; p < NPASS; ++p) {
      const uint32_t* C = PC[p].c;
      const uint32_t x1b = cb + C[1];
      float* hb = hb2 + (p & 1) * (NTHR * 5);    // double-buffered: 1 sync per pass
      hb[wsl + 0] = v0; hb[wsl + 1] = v1; hb[wsl + 2] = v6; hb[wsl + 3] = v7;
      __syncthreads();
      const float lh0 = hb[wl + 2], lh1 = hb[wl + 3];
      const float rh0 = hb[wr + 0], rh1 = hb[wr + 1];

      const float n0 = upd_sel(lh0, lh1, v0, v1, v2, y0, rough_hash(x1b + 0u, C));
      const float n1 = upd_sel(lh1, v0, v1, v2, v3, y1, rough_hash(x1b + 1u, C));
      const float n2 = upd_sel(v0, v1, v2, v3, v4, y2, rough_hash(x1b + 2u, C));
      const float n3 = upd_sel(v1, v2, v3, v4, v5, y3, rough_hash(x1b + 3u, C));
      const float n4 = upd_sel(v2, v3, v4, v5, v6, y4, rough_hash(x1b + 4u, C));
      const float n5 = upd_sel(v3, v4, v5, v6, v7, y5, rough_hash(x1b + 5u, C));
      const float n6 = upd_sel(v4, v5, v6, v7, rh0, y6, rough_hash(x1b + 6u, C));
      const float n7 = upd_sel(v5, v6, v7, rh0, rh1, y7, rough_hash(x1b + 7u, C));
      v0 = n0; v1 = n1; v2 = n2; v3 = n3; v4 = n4; v5 = n5; v6 = n6; v7 = n7;
    }

    const int l0 = tid * CPT;
    if (l0 >= HALO && l0 + CPT <= HALO + TOUT) {
      *(float4*)(dst + gbase)     = make_float4(v0, v1, v2, v3);
      *(float4*)(dst + gbase + 4) = make_float4(v4, v5, v6, v7);
    } else {
      const float vv[CPT] = {v0, v1, v2, v3, v4, v5, v6, v7};
#pragma unroll
      for (int j = 0; j < CPT; ++j) {
        const int l = l0 + j;
        if (l >= HALO && l < HALO + TOUT) dst[gbase + j] = vv[j];
      }
    }
  } else {
    // edge blocks (first / tail): same register+exchange structure, but each
    // element applies the exact boundary formula every pass:
    //   g==0: copy; g==1: one-sided stencil; g>=n-2: reset to y; else interior.
    // Garbage margins / OOB slots never feed a valid output (trapezoid + boundary cut).
#pragma unroll 1
    for (int p = 0; p < NPASS; ++p) {
      const uint32_t* C = PC[p].c;
      const uint32_t x1b = cb + C[1];
      float* hb = hb2 + (p & 1) * (NTHR * 5);
      hb[wsl + 0] = v0; hb[wsl + 1] = v1; hb[wsl + 2] = v6; hb[wsl + 3] = v7;
      __syncthreads();
      const float lh0 = hb[wl + 2], lh1 = hb[wl + 3];
      const float rh0 = hb[wr + 0], rh1 = hb[wr + 1];

      const float m2a[CPT] = {lh0, lh1, v0, v1, v2, v3, v4, v5};
      const float m1a[CPT] = {lh1, v0, v1, v2, v3, v4, v5, v6};
      const float ca [CPT] = {v0, v1, v2, v3, v4, v5, v6, v7};
      const float p1a[CPT] = {v1, v2, v3, v4, v5, v6, v7, rh0};
      const float p2a[CPT] = {v2, v3, v4, v5, v6, v7, rh0, rh1};
      const float ya [CPT] = {y0, y1, y2, y3, y4, y5, y6, y7};
      float out[CPT];
#pragma unroll
      for (int j = 0; j < CPT; ++j) {
        const int g = gbase + j;
        const float c = ca[j], m1 = m1a[j], p1 = p1a[j], p2 = p2a[j], yv = ya[j];
        float o;
        if (g == 0) {
          o = c;
        } else if (g == 1) {
          const float st1 = -2.0f * m1 + 5.0f * c - 4.0f * p1 + p2;
          o = c + 0.1f * (0.5f * st1 + 0.5f * (c - yv));
        } else if (g >= n - 2) {
          o = yv;
        } else {
          o = upd_sel(m2a[j], m1, c, p1, p2, yv, rough_hash(x1b + (uint32_t)j, C));
        }
        out[j] = o;
      }
      v0 = out[0]; v1 = out[1]; v2 = out[2]; v3 = out[3];
      v4 = out[4]; v5 = out[5]; v6 = out[6]; v7 = out[7];
    }

    const float vv[CPT] = {v0, v1, v2, v3, v4, v5, v6, v7};
    const int l0 = tid * CPT;
#pragma unroll
    for (int j = 0; j < CPT; ++j) {
      const int l = l0 + j;
      const int g = gbase + j;
      if (l >= HALO && l < HALO + TOUT && g < n) dst[g] = vv[j];
    }
  }
}

extern "C" void kernel_launch(void* const* d_in, const int* in_sizes, int n_in,
                              void* d_out, int out_size, void* d_ws, size_t ws_size,
                              hipStream_t stream) {
  const float* y = (const float*)d_in[0];
  float* out = (float*)d_out;
  const int n = in_sizes[0];
  const int blocks = (n + TOUT - 1) / TOUT;
  rs_fused<<<blocks, NTHR, 0, stream>>>(y, out, n);
}